// Round 10
// baseline (285.049 us; speedup 1.0000x reference)
//
#include <hip/hip_runtime.h>
#include <hip/hip_bf16.h>

#define EPS 1e-5f

typedef __attribute__((ext_vector_type(8))) short bf16x8;
typedef __attribute__((ext_vector_type(4))) float f32x4;

__device__ __forceinline__ ushort f2b(float f) {
    return __builtin_bit_cast(ushort, __float2bfloat16(f));
}
__device__ __forceinline__ bf16x8 ld_frag(const void* p) {
    return __builtin_bit_cast(bf16x8, *reinterpret_cast<const uint4*>(p));
}

// ================= fused prep =================
// BN folded into conv weights: wXp stores w*s[co] (bf16); bias[co] = bb - bm*s (fp32).
// jobs by blockIdx.x:
//  [0,128):    conv weights -> w1p/w2p/w3p (bf16, scaled) + bias arrays (bid 0)
//  [128,384):  fc weight transpose -> fcwp [256][8192] k'=p*128+c
//  [384,4480): x fp32 NCHW -> x4p bf16 [512][68][72][4]
//  [4480,4736): h1p border zero
//  [4736,4992): h2p border zero
__global__ __launch_bounds__(256) void k_prep_all(
    const float* __restrict__ w1, const float* __restrict__ w2,
    const float* __restrict__ w3, const float* __restrict__ fcw,
    const float* __restrict__ x,
    const float* __restrict__ bn1g, const float* __restrict__ bn1b,
    const float* __restrict__ bn1m, const float* __restrict__ bn1v,
    const float* __restrict__ bn2g, const float* __restrict__ bn2b,
    const float* __restrict__ bn2m, const float* __restrict__ bn2v,
    const float* __restrict__ bn3g, const float* __restrict__ bn3b,
    const float* __restrict__ bn3m, const float* __restrict__ bn3v,
    ushort* __restrict__ w1p, ushort* __restrict__ w2p, ushort* __restrict__ w3p,
    float* __restrict__ b1f, float* __restrict__ b2f, float* __restrict__ b3f,
    ushort* __restrict__ fcwp, ushort* __restrict__ x4p,
    ushort* __restrict__ h1p, ushort* __restrict__ h2p)
{
    __shared__ ushort l[128 * 66];
    const int bid = blockIdx.x, t = threadIdx.x;
    if (bid < 128) {
        if (bid == 0 && t < 224) {
            if (t < 32) {
                const float s = bn1g[t] * rsqrtf(bn1v[t] + EPS);
                b1f[t] = bn1b[t] - bn1m[t] * s;
            } else if (t < 96) {
                const int c = t - 32;
                const float s = bn2g[c] * rsqrtf(bn2v[c] + EPS);
                b2f[c] = bn2b[c] - bn2m[c] * s;
            } else {
                const int c = t - 96;
                const float s = bn3g[c] * rsqrtf(bn3v[c] + EPS);
                b3f[c] = bn3b[c] - bn3m[c] * s;
            }
        }
        const int total = 5120 + 18432 + 73728;
        for (int i = bid * 256 + t; i < total; i += 128 * 256) {
            if (i < 5120) {
                const int ky = i >> 10, co = (i >> 5) & 31, k = i & 31;
                const int kx = k >> 2, ci = k & 3;
                float v = 0.f;
                if (kx < 5 && ci < 3) v = w1[((co * 3 + ci) * 5 + ky) * 5 + kx];
                const float s = bn1g[co] * rsqrtf(bn1v[co] + EPS);
                w1p[i] = f2b(v * s);
            } else if (i < 5120 + 18432) {
                const int j = i - 5120;
                const int tap = j >> 11, co = (j >> 5) & 63, ci = j & 31;
                const float s = bn2g[co] * rsqrtf(bn2v[co] + EPS);
                w2p[j] = f2b(w2[(co * 32 + ci) * 9 + tap] * s);
            } else {
                const int j = i - (5120 + 18432);
                const int tap = j >> 13, co = (j >> 6) & 127, ci = j & 63;
                const float s = bn3g[co] * rsqrtf(bn3v[co] + EPS);
                w3p[j] = f2b(w3[(co * 64 + ci) * 9 + tap] * s);
            }
        }
    } else if (bid < 384) {
        const int j = bid - 128;
        const float* src = fcw + (size_t)j * 8192;
        #pragma unroll
        for (int i = 0; i < 32; ++i) {
            const int idx = i * 256 + t;
            const int c = idx >> 6, p = idx & 63;
            l[c * 66 + p] = f2b(src[idx]);
        }
        __syncthreads();
        ushort* dst = fcwp + (size_t)j * 8192;
        #pragma unroll
        for (int i = 0; i < 32; ++i) {
            const int idx = i * 256 + t;
            const int c = idx & 127, p = idx >> 7;
            dst[idx] = l[c * 66 + p];
        }
    } else if (bid < 4480) {
        for (int p = (bid - 384) * 256 + t; p < 2506752; p += 4096 * 256) {
            const int n = p / 4896;
            const int rem = p - n * 4896;
            const int row = rem / 72, col = rem - row * 72;
            const int gr = row - 2, gc = col - 2;
            ushort4 pk; pk.x = 0; pk.y = 0; pk.z = 0; pk.w = 0;
            if ((unsigned)gr < 64u && (unsigned)gc < 64u) {
                const size_t base = ((size_t)n * 3 << 12) + (gr << 6) + gc;
                pk.x = f2b(x[base]); pk.y = f2b(x[base + 4096]); pk.z = f2b(x[base + 8192]);
            }
            *reinterpret_cast<ushort4*>(&x4p[(size_t)p * 4]) = pk;
        }
    } else if (bid < 4736) {
        const uint4 z = {0, 0, 0, 0};
        for (int i = (bid - 4480) * 256 + t; i < 270336; i += 256 * 256) {
            const int img = i / 528;
            const int rem = i - img * 528;
            const int px = rem >> 2, gg = rem & 3;
            int row, col;
            if (px < 34)      { row = 0;  col = px; }
            else if (px < 68) { row = 33; col = px - 34; }
            else { const int q = px - 68; row = 1 + (q >> 1); col = (q & 1) ? 33 : 0; }
            *reinterpret_cast<uint4*>(&h1p[(((size_t)img * 34 + row) * 34 + col) * 32 + gg * 8]) = z;
        }
    } else if (bid < 4992) {
        const uint4 z = {0, 0, 0, 0};
        for (int i = (bid - 4736) * 256 + t; i < 278528; i += 256 * 256) {
            const int img = i / 544;
            const int rem = i - img * 544;
            const int px = rem >> 3, gg = rem & 7;
            int row, col;
            if (px < 18)      { row = 0;  col = px; }
            else if (px < 36) { row = 17; col = px - 18; }
            else { const int q = px - 36; row = 1 + (q >> 1); col = (q & 1) ? 17 : 0; }
            *reinterpret_cast<uint4*>(&h2p[(((size_t)img * 18 + row) * 18 + col) * 64 + gg * 8]) = z;
        }
    }
}

// ================= conv1: LDS activations, DIRECT global weights, folded BN ==========
__global__ __launch_bounds__(256, 4) void k_conv1(
    const ushort* __restrict__ x4p, const ushort* __restrict__ w1p,
    const float* __restrict__ bias, ushort* __restrict__ h1p)
{
    __shared__ __align__(16) ushort xs[12 * 72 * 4];   // 6912 B
    const int bid = blockIdx.x;
    const int n = bid >> 3, q = bid & 7;
    const int t = threadIdx.x;
    const int wave = t >> 6, lane = t & 63;
    const int g = lane >> 4, l15 = lane & 15;

    {
        const ushort* src = x4p + ((size_t)(n * 68 + 8 * q) * 72) * 4;
        for (int i = t; i < 432; i += 256)
            *reinterpret_cast<uint4*>(&xs[i * 8]) = *reinterpret_cast<const uint4*>(src + i * 8);
    }
    __syncthreads();

    f32x4 acc[8][2];
    #pragma unroll
    for (int i = 0; i < 8; ++i) { acc[i][0] = (f32x4){0,0,0,0}; acc[i][1] = (f32x4){0,0,0,0}; }

    const char* xsb = (const char*)xs;
    #pragma unroll
    for (int ky = 0; ky < 5; ++ky) {
        bf16x8 a[8], b[2];
        #pragma unroll
        for (int mt = 0; mt < 8; ++mt) {
            const int crl = 2 * wave + (mt >> 2);
            const int ccl = (mt & 3) * 16 + l15;
            const int off = ((crl + ky) * 72 + ccl) * 8 + g * 16;
            const uint2 lo = *reinterpret_cast<const uint2*>(xsb + off);
            const uint2 hi = *reinterpret_cast<const uint2*>(xsb + off + 8);
            uint4 all; all.x = lo.x; all.y = lo.y; all.z = hi.x; all.w = hi.y;
            a[mt] = __builtin_bit_cast(bf16x8, all);
        }
        #pragma unroll
        for (int nt = 0; nt < 2; ++nt) {
            const int co = nt * 16 + l15;
            b[nt] = ld_frag(&w1p[(ky * 32 + co) * 32 + g * 8]);
        }
        #pragma unroll
        for (int mt = 0; mt < 8; ++mt)
            #pragma unroll
            for (int nt = 0; nt < 2; ++nt)
                acc[mt][nt] = __builtin_amdgcn_mfma_f32_16x16x32_bf16(a[mt], b[nt], acc[mt][nt], 0, 0, 0);
    }

    const int prow = q * 4 + wave;
    #pragma unroll
    for (int nt = 0; nt < 2; ++nt) {
        const int co = nt * 16 + l15;
        const float bsv = bias[co];
        #pragma unroll
        for (int mt = 0; mt < 4; ++mt) {
            #pragma unroll
            for (int j = 0; j < 2; ++j) {
                const float v0 = fmaxf(acc[mt][nt][2 * j]     + bsv, 0.f);
                const float v1 = fmaxf(acc[mt][nt][2 * j + 1] + bsv, 0.f);
                const float v2 = fmaxf(acc[mt + 4][nt][2 * j]     + bsv, 0.f);
                const float v3 = fmaxf(acc[mt + 4][nt][2 * j + 1] + bsv, 0.f);
                const int ppc = mt * 8 + g * 2 + j;
                h1p[(((size_t)n * 34 + prow + 1) * 34 + ppc + 1) * 32 + co] =
                    f2b(fmaxf(fmaxf(v0, v1), fmaxf(v2, v3)));
            }
        }
    }
}

// ================= conv2: LDS activations, DIRECT global weights, folded BN ==========
__global__ __launch_bounds__(256, 4) void k_conv2(
    const ushort* __restrict__ h1p, const ushort* __restrict__ w2p,
    const float* __restrict__ bias, ushort* __restrict__ h2p)
{
    __shared__ __align__(16) ushort xs[10 * 34 * 32];  // 21760 B, swz by pix
    const int bid = blockIdx.x;
    const int n = bid >> 2, q = bid & 3;
    const int t = threadIdx.x;
    const int wave = t >> 6, lane = t & 63;
    const int g = lane >> 4, l15 = lane & 15;
    const char* xsb = (const char*)xs;

    {
        const ushort* src = h1p + ((size_t)(n * 34 + 8 * q) * 34) * 32;
        for (int i = t; i < 1360; i += 256) {
            const int gg = i & 3, pix = i >> 2;
            const uint4 v = *reinterpret_cast<const uint4*>(src + i * 8);
            *reinterpret_cast<uint4*>((char*)xs + pix * 64 + ((gg ^ ((pix >> 1) & 3)) << 4)) = v;
        }
    }
    __syncthreads();

    f32x4 acc[4][4];
    #pragma unroll
    for (int i = 0; i < 4; ++i)
        #pragma unroll
        for (int j = 0; j < 4; ++j) acc[i][j] = (f32x4){0,0,0,0};

    #pragma unroll
    for (int tap = 0; tap < 9; ++tap) {
        const int ky = tap / 3, kx = tap - 3 * ky;
        bf16x8 a[4], b[4];
        #pragma unroll
        for (int mt = 0; mt < 4; ++mt) {
            const int crl = 2 * wave + (mt >> 1);
            const int ccl = (mt & 1) * 16 + l15;
            const int pix = (crl + ky) * 34 + ccl + kx;
            a[mt] = ld_frag(xsb + pix * 64 + ((g ^ ((pix >> 1) & 3)) << 4));
        }
        #pragma unroll
        for (int nt = 0; nt < 4; ++nt) {
            const int co = nt * 16 + l15;
            b[nt] = ld_frag(&w2p[(tap * 64 + co) * 32 + g * 8]);
        }
        #pragma unroll
        for (int mt = 0; mt < 4; ++mt)
            #pragma unroll
            for (int nt = 0; nt < 4; ++nt)
                acc[mt][nt] = __builtin_amdgcn_mfma_f32_16x16x32_bf16(a[mt], b[nt], acc[mt][nt], 0, 0, 0);
    }

    const int prow = q * 4 + wave;
    #pragma unroll
    for (int nt = 0; nt < 4; ++nt) {
        const int co = nt * 16 + l15;
        const float bsv = bias[co];
        #pragma unroll
        for (int mtl = 0; mtl < 2; ++mtl) {
            #pragma unroll
            for (int j = 0; j < 2; ++j) {
                const float v0 = fmaxf(acc[mtl][nt][2 * j]     + bsv, 0.f);
                const float v1 = fmaxf(acc[mtl][nt][2 * j + 1] + bsv, 0.f);
                const float v2 = fmaxf(acc[mtl + 2][nt][2 * j]     + bsv, 0.f);
                const float v3 = fmaxf(acc[mtl + 2][nt][2 * j + 1] + bsv, 0.f);
                const int ppc = mtl * 8 + g * 2 + j;
                h2p[(((size_t)n * 18 + prow + 1) * 18 + ppc + 1) * 64 + co] =
                    f2b(fmaxf(fmaxf(v0, v1), fmaxf(v2, v3)));
            }
        }
    }
}

// ================= conv3: LDS activations, DIRECT global weights, folded BN ==========
__global__ __launch_bounds__(256, 4) void k_conv3(
    const ushort* __restrict__ h2p, const ushort* __restrict__ w3p,
    const float* __restrict__ bias, ushort* __restrict__ h3)
{
    __shared__ __align__(16) ushort xs[324 * 32];      // 20736 B, swz by pix
    const int bid = blockIdx.x;
    const int n = bid >> 1, ch = bid & 1;
    const int t = threadIdx.x;
    const int wave = t >> 6, lane = t & 63;
    const int g = lane >> 4, l15 = lane & 15;
    const char* xsb = (const char*)xs;

    f32x4 acc[4][4];
    #pragma unroll
    for (int i = 0; i < 4; ++i)
        #pragma unroll
        for (int j = 0; j < 4; ++j) acc[i][j] = (f32x4){0,0,0,0};

    for (int gci = 0; gci < 2; ++gci) {
        if (gci) __syncthreads();
        for (int i = t; i < 1296; i += 256) {
            const int gg = i & 3, pix = i >> 2;
            const uint4 v = *reinterpret_cast<const uint4*>(
                &h2p[((size_t)n * 324 + pix) * 64 + gci * 32 + gg * 8]);
            *reinterpret_cast<uint4*>((char*)xs + pix * 64 + ((gg ^ ((pix >> 1) & 3)) << 4)) = v;
        }
        __syncthreads();
        #pragma unroll
        for (int tap = 0; tap < 9; ++tap) {
            const int ky = tap / 3, kx = tap - 3 * ky;
            bf16x8 a[4], b[4];
            #pragma unroll
            for (int mt = 0; mt < 4; ++mt) {
                const int pr = 4 * wave + mt;
                const int pix = (pr + ky) * 18 + l15 + kx;
                a[mt] = ld_frag(xsb + pix * 64 + ((g ^ ((pix >> 1) & 3)) << 4));
            }
            #pragma unroll
            for (int nt = 0; nt < 4; ++nt) {
                const int co = ch * 64 + nt * 16 + l15;
                b[nt] = ld_frag(&w3p[((size_t)(tap * 128 + co)) * 64 + gci * 32 + g * 8]);
            }
            #pragma unroll
            for (int mt = 0; mt < 4; ++mt)
                #pragma unroll
                for (int nt = 0; nt < 4; ++nt)
                    acc[mt][nt] = __builtin_amdgcn_mfma_f32_16x16x32_bf16(a[mt], b[nt], acc[mt][nt], 0, 0, 0);
        }
    }

    #pragma unroll
    for (int nt = 0; nt < 4; ++nt) {
        const int co = ch * 64 + nt * 16 + l15;
        const float bsv = bias[co];
        #pragma unroll
        for (int mtl = 0; mtl < 2; ++mtl) {
            #pragma unroll
            for (int j = 0; j < 2; ++j) {
                const int mt = mtl * 2;
                const float v0 = fmaxf(acc[mt][nt][2 * j]     + bsv, 0.f);
                const float v1 = fmaxf(acc[mt][nt][2 * j + 1] + bsv, 0.f);
                const float v2 = fmaxf(acc[mt + 1][nt][2 * j]     + bsv, 0.f);
                const float v3 = fmaxf(acc[mt + 1][nt][2 * j + 1] + bsv, 0.f);
                const int ppr = 2 * wave + mtl;
                const int pcol = g * 2 + j;
                h3[(((size_t)n * 8 + ppr) * 8 + pcol) * 128 + co] =
                    f2b(fmaxf(fmaxf(v0, v1), fmaxf(v2, v3)));
            }
        }
    }
}

// ================= FC (unchanged): partials sr[16][512][256] =================
__global__ __launch_bounds__(256) void k_fc(
    const ushort* __restrict__ A, const ushort* __restrict__ Bw, float* __restrict__ C)
{
    __shared__ __align__(16) ushort As[64 * 32];
    __shared__ __align__(16) ushort Bs[64 * 32];
    const int bm = blockIdx.x, bn = blockIdx.y, kz = blockIdx.z;
    const int t = threadIdx.x;
    const int wave = t >> 6, lane = t & 63;
    const int g = lane >> 4, l15 = lane & 15;

    f32x4 acc[4];
    #pragma unroll
    for (int i = 0; i < 4; ++i) acc[i] = (f32x4){0,0,0,0};

    const char* asb = (const char*)As;
    const char* bsb = (const char*)Bs;
    for (int kk = 0; kk < 16; ++kk) {
        const int k0 = kz * 512 + kk * 32;
        if (kk) __syncthreads();
        {
            const int gg = t & 3, row = t >> 2;
            const uint4 va = *reinterpret_cast<const uint4*>(
                &A[(size_t)(bm * 64 + row) * 8192 + k0 + gg * 8]);
            *reinterpret_cast<uint4*>((char*)As + row * 64 + ((gg ^ ((row >> 1) & 3)) << 4)) = va;
            const uint4 vb = *reinterpret_cast<const uint4*>(
                &Bw[(size_t)(bn * 64 + row) * 8192 + k0 + gg * 8]);
            *reinterpret_cast<uint4*>((char*)Bs + row * 64 + ((gg ^ ((row >> 1) & 3)) << 4)) = vb;
        }
        __syncthreads();
        bf16x8 a[4], b;
        #pragma unroll
        for (int mt = 0; mt < 4; ++mt) {
            const int r = mt * 16 + l15;
            a[mt] = ld_frag(asb + r * 64 + ((g ^ ((r >> 1) & 3)) << 4));
        }
        {
            const int r = wave * 16 + l15;
            b = ld_frag(bsb + r * 64 + ((g ^ ((r >> 1) & 3)) << 4));
        }
        #pragma unroll
        for (int mt = 0; mt < 4; ++mt)
            acc[mt] = __builtin_amdgcn_mfma_f32_16x16x32_bf16(a[mt], b, acc[mt], 0, 0, 0);
    }

    float* Cp = C + (size_t)kz * 512 * 256;
    const int col = bn * 64 + wave * 16 + l15;
    #pragma unroll
    for (int mt = 0; mt < 4; ++mt) {
        #pragma unroll
        for (int r = 0; r < 4; ++r) {
            const int row = bm * 64 + mt * 16 + g * 4 + r;
            Cp[(size_t)row * 256 + col] = acc[mt][r];
        }
    }
}

// ================= heads (unchanged) =================
__global__ __launch_bounds__(128) void k_heads(
    const float* __restrict__ sraw, const float* __restrict__ fcb,
    const float* __restrict__ fg, const float* __restrict__ fb,
    const float* __restrict__ fm, const float* __restrict__ fv,
    const float* __restrict__ cw1, const float* __restrict__ cb1,
    const float* __restrict__ cg, const float* __restrict__ cbb,
    const float* __restrict__ cm, const float* __restrict__ cv,
    const float* __restrict__ cw2, const float* __restrict__ cb2,
    const float* __restrict__ mw1, const float* __restrict__ mb1,
    const float* __restrict__ mg, const float* __restrict__ mbb,
    const float* __restrict__ mm, const float* __restrict__ mv,
    const float* __restrict__ mw2, const float* __restrict__ mb2,
    float* __restrict__ outp)
{
    __shared__ float sv[256];
    const int b = blockIdx.x, t = threadIdx.x;
    for (int k = t; k < 256; k += 128) {
        float val = fcb[k];
        #pragma unroll
        for (int z = 0; z < 16; ++z) val += sraw[(size_t)z * 131072 + b * 256 + k];
        const float s = fg[k] * rsqrtf(fv[k] + EPS);
        sv[k] = fmaxf(fmaf(val, s, fb[k] - fm[k] * s), 0.f);
    }
    __syncthreads();
    const int j = t & 63;
    const bool isM = (t >= 64);
    const float* w1  = isM ? mw1 : cw1;
    const float* b1  = isM ? mb1 : cb1;
    const float* g1  = isM ? mg  : cg;
    const float* bb1 = isM ? mbb : cbb;
    const float* m1  = isM ? mm  : cm;
    const float* v1  = isM ? mv  : cv;
    const float* w2  = isM ? mw2 : cw2;
    const float* b2  = isM ? mb2 : cb2;
    float d = 0.f;
    const float* wr = w1 + j * 256;
    #pragma unroll 8
    for (int k = 0; k < 256; ++k) d = fmaf(sv[k], wr[k], d);
    d += b1[j];
    const float s1 = g1[j] * rsqrtf(v1[j] + EPS);
    d = fmaxf(fmaf(d, s1, bb1[j] - m1[j] * s1), 0.f);
    float prod = d * w2[j];
    #pragma unroll
    for (int off = 32; off > 0; off >>= 1) prod += __shfl_down(prod, off);
    if (j == 0) outp[(isM ? 512 : 0) + b] = prod + b2[0];
}

extern "C" void kernel_launch(void* const* d_in, const int* in_sizes, int n_in,
                              void* d_out, int out_size, void* d_ws, size_t ws_size,
                              hipStream_t stream)
{
    const float* x    = (const float*)d_in[0];
    const float* w1   = (const float*)d_in[1];
    const float* bn1g = (const float*)d_in[2];
    const float* bn1b = (const float*)d_in[3];
    const float* bn1m = (const float*)d_in[4];
    const float* bn1v = (const float*)d_in[5];
    const float* w2   = (const float*)d_in[6];
    const float* bn2g = (const float*)d_in[7];
    const float* bn2b = (const float*)d_in[8];
    const float* bn2m = (const float*)d_in[9];
    const float* bn2v = (const float*)d_in[10];
    const float* w3   = (const float*)d_in[11];
    const float* bn3g = (const float*)d_in[12];
    const float* bn3b = (const float*)d_in[13];
    const float* bn3m = (const float*)d_in[14];
    const float* bn3v = (const float*)d_in[15];
    const float* fcw  = (const float*)d_in[16];
    const float* fcb  = (const float*)d_in[17];
    const float* bnfg = (const float*)d_in[18];
    const float* bnfb = (const float*)d_in[19];
    const float* bnfm = (const float*)d_in[20];
    const float* bnfv = (const float*)d_in[21];
    const float* cw1  = (const float*)d_in[22];
    const float* cb1  = (const float*)d_in[23];
    const float* bncg = (const float*)d_in[24];
    const float* bncb = (const float*)d_in[25];
    const float* bncm = (const float*)d_in[26];
    const float* bncv = (const float*)d_in[27];
    const float* cw2  = (const float*)d_in[28];
    const float* cb2  = (const float*)d_in[29];
    const float* mw1  = (const float*)d_in[30];
    const float* mb1  = (const float*)d_in[31];
    const float* bnmg = (const float*)d_in[32];
    const float* bnmb = (const float*)d_in[33];
    const float* bnmm = (const float*)d_in[34];
    const float* bnmv = (const float*)d_in[35];
    const float* mw2  = (const float*)d_in[36];
    const float* mb2  = (const float*)d_in[37];

    char* W = (char*)d_ws;
    ushort* x4p  = (ushort*)(W);                 // 20,054,016 B
    ushort* h1p  = (ushort*)(W + 20054016);      // 37,879,808 B
    ushort* h2p  = (ushort*)(W + 57933824);      // 21,233,664 B
    ushort* h3   = (ushort*)(W + 79167488);      //  8,388,608 B
    ushort* w1p  = (ushort*)(W + 87556096);      //     10,240 B
    ushort* w2p  = (ushort*)(W + 87566336);      //     36,864 B
    ushort* w3p  = (ushort*)(W + 87603200);      //    147,456 B
    ushort* fcwp = (ushort*)(W + 87750656);      //  4,194,304 B
    float*  b1f  = (float*) (W + 91944960);      //        128 B
    float*  b2f  = (float*) (W + 91945088);      //        256 B
    float*  b3f  = (float*) (W + 91945344);      //        512 B
    float*  sr   = (float*) (W + 91946496);      //  8,388,608 B
    float* outp = (float*)d_out;

    k_prep_all<<<4992, 256, 0, stream>>>(w1, w2, w3, fcw, x,
                                         bn1g, bn1b, bn1m, bn1v,
                                         bn2g, bn2b, bn2m, bn2v,
                                         bn3g, bn3b, bn3m, bn3v,
                                         w1p, w2p, w3p, b1f, b2f, b3f,
                                         fcwp, x4p, h1p, h2p);
    k_conv1<<<512 * 8, 256, 0, stream>>>(x4p, w1p, b1f, h1p);
    k_conv2<<<512 * 4, 256, 0, stream>>>(h1p, w2p, b2f, h2p);
    k_conv3<<<512 * 2, 256, 0, stream>>>(h2p, w3p, b3f, h3);
    k_fc<<<dim3(8, 4, 16), 256, 0, stream>>>(h3, fcwp, sr);
    k_heads<<<512, 128, 0, stream>>>(sr, fcb, bnfg, bnfb, bnfm, bnfv,
                                     cw1, cb1, bncg, bncb, bncm, bncv, cw2, cb2,
                                     mw1, mb1, bnmg, bnmb, bnmm, bnmv, mw2, mb2, outp);
}

// Round 11
// 245.545 us; speedup vs baseline: 1.1609x; 1.1609x over previous
//
#include <hip/hip_runtime.h>
#include <hip/hip_bf16.h>

#define EPS 1e-5f

typedef __attribute__((ext_vector_type(8))) short bf16x8;
typedef __attribute__((ext_vector_type(4))) float f32x4;

__device__ __forceinline__ ushort f2b(float f) {
    return __builtin_bit_cast(ushort, __float2bfloat16(f));
}
__device__ __forceinline__ bf16x8 ld_frag(const void* p) {
    return __builtin_bit_cast(bf16x8, *reinterpret_cast<const uint4*>(p));
}

// ================= fused prep (folded BN; unchanged from r10) =================
__global__ __launch_bounds__(256) void k_prep_all(
    const float* __restrict__ w1, const float* __restrict__ w2,
    const float* __restrict__ w3, const float* __restrict__ fcw,
    const float* __restrict__ x,
    const float* __restrict__ bn1g, const float* __restrict__ bn1b,
    const float* __restrict__ bn1m, const float* __restrict__ bn1v,
    const float* __restrict__ bn2g, const float* __restrict__ bn2b,
    const float* __restrict__ bn2m, const float* __restrict__ bn2v,
    const float* __restrict__ bn3g, const float* __restrict__ bn3b,
    const float* __restrict__ bn3m, const float* __restrict__ bn3v,
    ushort* __restrict__ w1p, ushort* __restrict__ w2p, ushort* __restrict__ w3p,
    float* __restrict__ b1f, float* __restrict__ b2f, float* __restrict__ b3f,
    ushort* __restrict__ fcwp, ushort* __restrict__ x4p,
    ushort* __restrict__ h1p, ushort* __restrict__ h2p)
{
    __shared__ ushort l[128 * 66];
    const int bid = blockIdx.x, t = threadIdx.x;
    if (bid < 128) {
        if (bid == 0 && t < 224) {
            if (t < 32) {
                const float s = bn1g[t] * rsqrtf(bn1v[t] + EPS);
                b1f[t] = bn1b[t] - bn1m[t] * s;
            } else if (t < 96) {
                const int c = t - 32;
                const float s = bn2g[c] * rsqrtf(bn2v[c] + EPS);
                b2f[c] = bn2b[c] - bn2m[c] * s;
            } else {
                const int c = t - 96;
                const float s = bn3g[c] * rsqrtf(bn3v[c] + EPS);
                b3f[c] = bn3b[c] - bn3m[c] * s;
            }
        }
        const int total = 5120 + 18432 + 73728;
        for (int i = bid * 256 + t; i < total; i += 128 * 256) {
            if (i < 5120) {
                const int ky = i >> 10, co = (i >> 5) & 31, k = i & 31;
                const int kx = k >> 2, ci = k & 3;
                float v = 0.f;
                if (kx < 5 && ci < 3) v = w1[((co * 3 + ci) * 5 + ky) * 5 + kx];
                const float s = bn1g[co] * rsqrtf(bn1v[co] + EPS);
                w1p[i] = f2b(v * s);
            } else if (i < 5120 + 18432) {
                const int j = i - 5120;
                const int tap = j >> 11, co = (j >> 5) & 63, ci = j & 31;
                const float s = bn2g[co] * rsqrtf(bn2v[co] + EPS);
                w2p[j] = f2b(w2[(co * 32 + ci) * 9 + tap] * s);
            } else {
                const int j = i - (5120 + 18432);
                const int tap = j >> 13, co = (j >> 6) & 127, ci = j & 63;
                const float s = bn3g[co] * rsqrtf(bn3v[co] + EPS);
                w3p[j] = f2b(w3[(co * 64 + ci) * 9 + tap] * s);
            }
        }
    } else if (bid < 384) {
        const int j = bid - 128;
        const float* src = fcw + (size_t)j * 8192;
        #pragma unroll
        for (int i = 0; i < 32; ++i) {
            const int idx = i * 256 + t;
            const int c = idx >> 6, p = idx & 63;
            l[c * 66 + p] = f2b(src[idx]);
        }
        __syncthreads();
        ushort* dst = fcwp + (size_t)j * 8192;
        #pragma unroll
        for (int i = 0; i < 32; ++i) {
            const int idx = i * 256 + t;
            const int c = idx & 127, p = idx >> 7;
            dst[idx] = l[c * 66 + p];
        }
    } else if (bid < 4480) {
        for (int p = (bid - 384) * 256 + t; p < 2506752; p += 4096 * 256) {
            const int n = p / 4896;
            const int rem = p - n * 4896;
            const int row = rem / 72, col = rem - row * 72;
            const int gr = row - 2, gc = col - 2;
            ushort4 pk; pk.x = 0; pk.y = 0; pk.z = 0; pk.w = 0;
            if ((unsigned)gr < 64u && (unsigned)gc < 64u) {
                const size_t base = ((size_t)n * 3 << 12) + (gr << 6) + gc;
                pk.x = f2b(x[base]); pk.y = f2b(x[base + 4096]); pk.z = f2b(x[base + 8192]);
            }
            *reinterpret_cast<ushort4*>(&x4p[(size_t)p * 4]) = pk;
        }
    } else if (bid < 4736) {
        const uint4 z = {0, 0, 0, 0};
        for (int i = (bid - 4480) * 256 + t; i < 270336; i += 256 * 256) {
            const int img = i / 528;
            const int rem = i - img * 528;
            const int px = rem >> 2, gg = rem & 3;
            int row, col;
            if (px < 34)      { row = 0;  col = px; }
            else if (px < 68) { row = 33; col = px - 34; }
            else { const int q = px - 68; row = 1 + (q >> 1); col = (q & 1) ? 33 : 0; }
            *reinterpret_cast<uint4*>(&h1p[(((size_t)img * 34 + row) * 34 + col) * 32 + gg * 8]) = z;
        }
    } else if (bid < 4992) {
        const uint4 z = {0, 0, 0, 0};
        for (int i = (bid - 4736) * 256 + t; i < 278528; i += 256 * 256) {
            const int img = i / 544;
            const int rem = i - img * 544;
            const int px = rem >> 3, gg = rem & 7;
            int row, col;
            if (px < 18)      { row = 0;  col = px; }
            else if (px < 36) { row = 17; col = px - 18; }
            else { const int q = px - 36; row = 1 + (q >> 1); col = (q & 1) ? 17 : 0; }
            *reinterpret_cast<uint4*>(&h2p[(((size_t)img * 18 + row) * 18 + col) * 64 + gg * 8]) = z;
        }
    }
}

// ================= conv1: LDS act + LDS weights (r9 structure), folded BN =============
__global__ __launch_bounds__(256) void k_conv1(
    const ushort* __restrict__ x4p, const ushort* __restrict__ w1p,
    const float* __restrict__ bias, ushort* __restrict__ h1p)
{
    __shared__ __align__(16) ushort xs[12 * 72 * 4];   // 6912 B
    __shared__ __align__(16) ushort ws[5 * 32 * 32];   // 10240 B
    const int bid = blockIdx.x;
    const int n = bid >> 3, q = bid & 7;
    const int t = threadIdx.x;
    const int wave = t >> 6, lane = t & 63;
    const int g = lane >> 4, l15 = lane & 15;

    {
        const ushort* src = x4p + ((size_t)(n * 68 + 8 * q) * 72) * 4;
        for (int i = t; i < 432; i += 256)
            *reinterpret_cast<uint4*>(&xs[i * 8]) = *reinterpret_cast<const uint4*>(src + i * 8);
    }
    for (int i = t; i < 640; i += 256) {
        const int gg = i & 3, r = i >> 2;
        const int co = r & 31;
        const uint4 v = *reinterpret_cast<const uint4*>(&w1p[r * 32 + gg * 8]);
        *reinterpret_cast<uint4*>((char*)ws + r * 64 + ((gg ^ ((co >> 1) & 3)) << 4)) = v;
    }
    __syncthreads();

    f32x4 acc[8][2];
    #pragma unroll
    for (int i = 0; i < 8; ++i) { acc[i][0] = (f32x4){0,0,0,0}; acc[i][1] = (f32x4){0,0,0,0}; }

    const char* xsb = (const char*)xs;
    const char* wsb = (const char*)ws;
    #pragma unroll
    for (int ky = 0; ky < 5; ++ky) {
        bf16x8 a[8], b[2];
        #pragma unroll
        for (int mt = 0; mt < 8; ++mt) {
            const int crl = 2 * wave + (mt >> 2);
            const int ccl = (mt & 3) * 16 + l15;
            const int off = ((crl + ky) * 72 + ccl) * 8 + g * 16;
            const uint2 lo = *reinterpret_cast<const uint2*>(xsb + off);
            const uint2 hi = *reinterpret_cast<const uint2*>(xsb + off + 8);
            uint4 all; all.x = lo.x; all.y = lo.y; all.z = hi.x; all.w = hi.y;
            a[mt] = __builtin_bit_cast(bf16x8, all);
        }
        #pragma unroll
        for (int nt = 0; nt < 2; ++nt) {
            const int co = nt * 16 + l15;
            b[nt] = ld_frag(wsb + (ky * 32 + co) * 64 + ((g ^ ((co >> 1) & 3)) << 4));
        }
        #pragma unroll
        for (int mt = 0; mt < 8; ++mt)
            #pragma unroll
            for (int nt = 0; nt < 2; ++nt)
                acc[mt][nt] = __builtin_amdgcn_mfma_f32_16x16x32_bf16(a[mt], b[nt], acc[mt][nt], 0, 0, 0);
    }

    const int prow = q * 4 + wave;
    #pragma unroll
    for (int nt = 0; nt < 2; ++nt) {
        const int co = nt * 16 + l15;
        const float bsv = bias[co];
        #pragma unroll
        for (int mt = 0; mt < 4; ++mt) {
            #pragma unroll
            for (int j = 0; j < 2; ++j) {
                const float v0 = fmaxf(acc[mt][nt][2 * j]     + bsv, 0.f);
                const float v1 = fmaxf(acc[mt][nt][2 * j + 1] + bsv, 0.f);
                const float v2 = fmaxf(acc[mt + 4][nt][2 * j]     + bsv, 0.f);
                const float v3 = fmaxf(acc[mt + 4][nt][2 * j + 1] + bsv, 0.f);
                const int ppc = mt * 8 + g * 2 + j;
                h1p[(((size_t)n * 34 + prow + 1) * 34 + ppc + 1) * 32 + co] =
                    f2b(fmaxf(fmaxf(v0, v1), fmaxf(v2, v3)));
            }
        }
    }
}

// ===== conv2: LDS act + LDS weights in 3-tap (one-ky) chunks -> 34 KB, 4 blocks/CU ====
__global__ __launch_bounds__(256) void k_conv2(
    const ushort* __restrict__ h1p, const ushort* __restrict__ w2p,
    const float* __restrict__ bias, ushort* __restrict__ h2p)
{
    __shared__ __align__(16) ushort xs[10 * 34 * 32];  // 21760 B, swz by pix
    __shared__ __align__(16) ushort ws[3 * 64 * 32];   // 12288 B, swz by co
    const int bid = blockIdx.x;
    const int n = bid >> 2, q = bid & 3;
    const int t = threadIdx.x;
    const int wave = t >> 6, lane = t & 63;
    const int g = lane >> 4, l15 = lane & 15;
    const char* xsb = (const char*)xs;
    const char* wsb = (const char*)ws;

    {
        const ushort* src = h1p + ((size_t)(n * 34 + 8 * q) * 34) * 32;
        for (int i = t; i < 1360; i += 256) {
            const int gg = i & 3, pix = i >> 2;
            const uint4 v = *reinterpret_cast<const uint4*>(src + i * 8);
            *reinterpret_cast<uint4*>((char*)xs + pix * 64 + ((gg ^ ((pix >> 1) & 3)) << 4)) = v;
        }
    }

    f32x4 acc[4][4];
    #pragma unroll
    for (int i = 0; i < 4; ++i)
        #pragma unroll
        for (int j = 0; j < 4; ++j) acc[i][j] = (f32x4){0,0,0,0};

    for (int ky = 0; ky < 3; ++ky) {
        if (ky) __syncthreads();               // protect ws overwrite
        for (int i = t; i < 768; i += 256) {   // taps ky*3..ky*3+2 (192 rows x 4 granules)
            const int gg = i & 3, rl = i >> 2;
            const int co = rl & 63;
            const uint4 v = *reinterpret_cast<const uint4*>(&w2p[(ky * 192 + rl) * 32 + gg * 8]);
            *reinterpret_cast<uint4*>((char*)ws + rl * 64 + ((gg ^ ((co >> 1) & 3)) << 4)) = v;
        }
        __syncthreads();
        #pragma unroll
        for (int kx = 0; kx < 3; ++kx) {
            bf16x8 a[4], b[4];
            #pragma unroll
            for (int mt = 0; mt < 4; ++mt) {
                const int crl = 2 * wave + (mt >> 1);
                const int ccl = (mt & 1) * 16 + l15;
                const int pix = (crl + ky) * 34 + ccl + kx;
                a[mt] = ld_frag(xsb + pix * 64 + ((g ^ ((pix >> 1) & 3)) << 4));
            }
            #pragma unroll
            for (int nt = 0; nt < 4; ++nt) {
                const int co = nt * 16 + l15;
                b[nt] = ld_frag(wsb + (kx * 64 + co) * 64 + ((g ^ ((co >> 1) & 3)) << 4));
            }
            #pragma unroll
            for (int mt = 0; mt < 4; ++mt)
                #pragma unroll
                for (int nt = 0; nt < 4; ++nt)
                    acc[mt][nt] = __builtin_amdgcn_mfma_f32_16x16x32_bf16(a[mt], b[nt], acc[mt][nt], 0, 0, 0);
        }
    }

    const int prow = q * 4 + wave;
    #pragma unroll
    for (int nt = 0; nt < 4; ++nt) {
        const int co = nt * 16 + l15;
        const float bsv = bias[co];
        #pragma unroll
        for (int mtl = 0; mtl < 2; ++mtl) {
            #pragma unroll
            for (int j = 0; j < 2; ++j) {
                const float v0 = fmaxf(acc[mtl][nt][2 * j]     + bsv, 0.f);
                const float v1 = fmaxf(acc[mtl][nt][2 * j + 1] + bsv, 0.f);
                const float v2 = fmaxf(acc[mtl + 2][nt][2 * j]     + bsv, 0.f);
                const float v3 = fmaxf(acc[mtl + 2][nt][2 * j + 1] + bsv, 0.f);
                const int ppc = mtl * 8 + g * 2 + j;
                h2p[(((size_t)n * 18 + prow + 1) * 18 + ppc + 1) * 64 + co] =
                    f2b(fmaxf(fmaxf(v0, v1), fmaxf(v2, v3)));
            }
        }
    }
}

// ===== conv3: LDS act + LDS weights in 3-tap chunks per ci-half -> 33 KB, 4 blocks/CU ==
__global__ __launch_bounds__(256) void k_conv3(
    const ushort* __restrict__ h2p, const ushort* __restrict__ w3p,
    const float* __restrict__ bias, ushort* __restrict__ h3)
{
    __shared__ __align__(16) ushort xs[324 * 32];      // 20736 B, swz by pix
    __shared__ __align__(16) ushort ws[3 * 64 * 32];   // 12288 B, swz by co
    const int bid = blockIdx.x;
    const int n = bid >> 1, ch = bid & 1;
    const int t = threadIdx.x;
    const int wave = t >> 6, lane = t & 63;
    const int g = lane >> 4, l15 = lane & 15;
    const char* xsb = (const char*)xs;
    const char* wsb = (const char*)ws;

    f32x4 acc[4][4];
    #pragma unroll
    for (int i = 0; i < 4; ++i)
        #pragma unroll
        for (int j = 0; j < 4; ++j) acc[i][j] = (f32x4){0,0,0,0};

    for (int gci = 0; gci < 2; ++gci) {
        for (int ky = 0; ky < 3; ++ky) {
            if (gci || ky) __syncthreads();    // protect xs/ws overwrite
            if (ky == 0) {
                for (int i = t; i < 1296; i += 256) {
                    const int gg = i & 3, pix = i >> 2;
                    const uint4 v = *reinterpret_cast<const uint4*>(
                        &h2p[((size_t)n * 324 + pix) * 64 + gci * 32 + gg * 8]);
                    *reinterpret_cast<uint4*>((char*)xs + pix * 64 + ((gg ^ ((pix >> 1) & 3)) << 4)) = v;
                }
            }
            for (int i = t; i < 768; i += 256) {
                const int gg = i & 3, rl = i >> 2;      // rl = tapl*64+co, tapl<3
                const int tapl = rl >> 6, co = rl & 63;
                const uint4 v = *reinterpret_cast<const uint4*>(
                    &w3p[((size_t)((ky * 3 + tapl) * 128 + ch * 64 + co) << 6) + gci * 32 + gg * 8]);
                *reinterpret_cast<uint4*>((char*)ws + rl * 64 + ((gg ^ ((co >> 1) & 3)) << 4)) = v;
            }
            __syncthreads();
            #pragma unroll
            for (int kx = 0; kx < 3; ++kx) {
                bf16x8 a[4], b[4];
                #pragma unroll
                for (int mt = 0; mt < 4; ++mt) {
                    const int pr = 4 * wave + mt;
                    const int pix = (pr + ky) * 18 + l15 + kx;
                    a[mt] = ld_frag(xsb + pix * 64 + ((g ^ ((pix >> 1) & 3)) << 4));
                }
                #pragma unroll
                for (int nt = 0; nt < 4; ++nt) {
                    const int co = nt * 16 + l15;
                    b[nt] = ld_frag(wsb + (kx * 64 + co) * 64 + ((g ^ ((co >> 1) & 3)) << 4));
                }
                #pragma unroll
                for (int mt = 0; mt < 4; ++mt)
                    #pragma unroll
                    for (int nt = 0; nt < 4; ++nt)
                        acc[mt][nt] = __builtin_amdgcn_mfma_f32_16x16x32_bf16(a[mt], b[nt], acc[mt][nt], 0, 0, 0);
            }
        }
    }

    #pragma unroll
    for (int nt = 0; nt < 4; ++nt) {
        const int co = ch * 64 + nt * 16 + l15;
        const float bsv = bias[co];
        #pragma unroll
        for (int mtl = 0; mtl < 2; ++mtl) {
            #pragma unroll
            for (int j = 0; j < 2; ++j) {
                const int mt = mtl * 2;
                const float v0 = fmaxf(acc[mt][nt][2 * j]     + bsv, 0.f);
                const float v1 = fmaxf(acc[mt][nt][2 * j + 1] + bsv, 0.f);
                const float v2 = fmaxf(acc[mt + 1][nt][2 * j]     + bsv, 0.f);
                const float v3 = fmaxf(acc[mt + 1][nt][2 * j + 1] + bsv, 0.f);
                const int ppr = 2 * wave + mtl;
                const int pcol = g * 2 + j;
                h3[(((size_t)n * 8 + ppr) * 8 + pcol) * 128 + co] =
                    f2b(fmaxf(fmaxf(v0, v1), fmaxf(v2, v3)));
            }
        }
    }
}

// ================= FC (unchanged): partials sr[16][512][256] =================
__global__ __launch_bounds__(256) void k_fc(
    const ushort* __restrict__ A, const ushort* __restrict__ Bw, float* __restrict__ C)
{
    __shared__ __align__(16) ushort As[64 * 32];
    __shared__ __align__(16) ushort Bs[64 * 32];
    const int bm = blockIdx.x, bn = blockIdx.y, kz = blockIdx.z;
    const int t = threadIdx.x;
    const int wave = t >> 6, lane = t & 63;
    const int g = lane >> 4, l15 = lane & 15;

    f32x4 acc[4];
    #pragma unroll
    for (int i = 0; i < 4; ++i) acc[i] = (f32x4){0,0,0,0};

    const char* asb = (const char*)As;
    const char* bsb = (const char*)Bs;
    for (int kk = 0; kk < 16; ++kk) {
        const int k0 = kz * 512 + kk * 32;
        if (kk) __syncthreads();
        {
            const int gg = t & 3, row = t >> 2;
            const uint4 va = *reinterpret_cast<const uint4*>(
                &A[(size_t)(bm * 64 + row) * 8192 + k0 + gg * 8]);
            *reinterpret_cast<uint4*>((char*)As + row * 64 + ((gg ^ ((row >> 1) & 3)) << 4)) = va;
            const uint4 vb = *reinterpret_cast<const uint4*>(
                &Bw[(size_t)(bn * 64 + row) * 8192 + k0 + gg * 8]);
            *reinterpret_cast<uint4*>((char*)Bs + row * 64 + ((gg ^ ((row >> 1) & 3)) << 4)) = vb;
        }
        __syncthreads();
        bf16x8 a[4], b;
        #pragma unroll
        for (int mt = 0; mt < 4; ++mt) {
            const int r = mt * 16 + l15;
            a[mt] = ld_frag(asb + r * 64 + ((g ^ ((r >> 1) & 3)) << 4));
        }
        {
            const int r = wave * 16 + l15;
            b = ld_frag(bsb + r * 64 + ((g ^ ((r >> 1) & 3)) << 4));
        }
        #pragma unroll
        for (int mt = 0; mt < 4; ++mt)
            acc[mt] = __builtin_amdgcn_mfma_f32_16x16x32_bf16(a[mt], b, acc[mt], 0, 0, 0);
    }

    float* Cp = C + (size_t)kz * 512 * 256;
    const int col = bn * 64 + wave * 16 + l15;
    #pragma unroll
    for (int mt = 0; mt < 4; ++mt) {
        #pragma unroll
        for (int r = 0; r < 4; ++r) {
            const int row = bm * 64 + mt * 16 + g * 4 + r;
            Cp[(size_t)row * 256 + col] = acc[mt][r];
        }
    }
}

// ================= heads (unchanged) =================
__global__ __launch_bounds__(128) void k_heads(
    const float* __restrict__ sraw, const float* __restrict__ fcb,
    const float* __restrict__ fg, const float* __restrict__ fb,
    const float* __restrict__ fm, const float* __restrict__ fv,
    const float* __restrict__ cw1, const float* __restrict__ cb1,
    const float* __restrict__ cg, const float* __restrict__ cbb,
    const float* __restrict__ cm, const float* __restrict__ cv,
    const float* __restrict__ cw2, const float* __restrict__ cb2,
    const float* __restrict__ mw1, const float* __restrict__ mb1,
    const float* __restrict__ mg, const float* __restrict__ mbb,
    const float* __restrict__ mm, const float* __restrict__ mv,
    const float* __restrict__ mw2, const float* __restrict__ mb2,
    float* __restrict__ outp)
{
    __shared__ float sv[256];
    const int b = blockIdx.x, t = threadIdx.x;
    for (int k = t; k < 256; k += 128) {
        float val = fcb[k];
        #pragma unroll
        for (int z = 0; z < 16; ++z) val += sraw[(size_t)z * 131072 + b * 256 + k];
        const float s = fg[k] * rsqrtf(fv[k] + EPS);
        sv[k] = fmaxf(fmaf(val, s, fb[k] - fm[k] * s), 0.f);
    }
    __syncthreads();
    const int j = t & 63;
    const bool isM = (t >= 64);
    const float* w1  = isM ? mw1 : cw1;
    const float* b1  = isM ? mb1 : cb1;
    const float* g1  = isM ? mg  : cg;
    const float* bb1 = isM ? mbb : cbb;
    const float* m1  = isM ? mm  : cm;
    const float* v1  = isM ? mv  : cv;
    const float* w2  = isM ? mw2 : cw2;
    const float* b2  = isM ? mb2 : cb2;
    float d = 0.f;
    const float* wr = w1 + j * 256;
    #pragma unroll 8
    for (int k = 0; k < 256; ++k) d = fmaf(sv[k], wr[k], d);
    d += b1[j];
    const float s1 = g1[j] * rsqrtf(v1[j] + EPS);
    d = fmaxf(fmaf(d, s1, bb1[j] - m1[j] * s1), 0.f);
    float prod = d * w2[j];
    #pragma unroll
    for (int off = 32; off > 0; off >>= 1) prod += __shfl_down(prod, off);
    if (j == 0) outp[(isM ? 512 : 0) + b] = prod + b2[0];
}

extern "C" void kernel_launch(void* const* d_in, const int* in_sizes, int n_in,
                              void* d_out, int out_size, void* d_ws, size_t ws_size,
                              hipStream_t stream)
{
    const float* x    = (const float*)d_in[0];
    const float* w1   = (const float*)d_in[1];
    const float* bn1g = (const float*)d_in[2];
    const float* bn1b = (const float*)d_in[3];
    const float* bn1m = (const float*)d_in[4];
    const float* bn1v = (const float*)d_in[5];
    const float* w2   = (const float*)d_in[6];
    const float* bn2g = (const float*)d_in[7];
    const float* bn2b = (const float*)d_in[8];
    const float* bn2m = (const float*)d_in[9];
    const float* bn2v = (const float*)d_in[10];
    const float* w3   = (const float*)d_in[11];
    const float* bn3g = (const float*)d_in[12];
    const float* bn3b = (const float*)d_in[13];
    const float* bn3m = (const float*)d_in[14];
    const float* bn3v = (const float*)d_in[15];
    const float* fcw  = (const float*)d_in[16];
    const float* fcb  = (const float*)d_in[17];
    const float* bnfg = (const float*)d_in[18];
    const float* bnfb = (const float*)d_in[19];
    const float* bnfm = (const float*)d_in[20];
    const float* bnfv = (const float*)d_in[21];
    const float* cw1  = (const float*)d_in[22];
    const float* cb1  = (const float*)d_in[23];
    const float* bncg = (const float*)d_in[24];
    const float* bncb = (const float*)d_in[25];
    const float* bncm = (const float*)d_in[26];
    const float* bncv = (const float*)d_in[27];
    const float* cw2  = (const float*)d_in[28];
    const float* cb2  = (const float*)d_in[29];
    const float* mw1  = (const float*)d_in[30];
    const float* mb1  = (const float*)d_in[31];
    const float* bnmg = (const float*)d_in[32];
    const float* bnmb = (const float*)d_in[33];
    const float* bnmm = (const float*)d_in[34];
    const float* bnmv = (const float*)d_in[35];
    const float* mw2  = (const float*)d_in[36];
    const float* mb2  = (const float*)d_in[37];

    char* W = (char*)d_ws;
    ushort* x4p  = (ushort*)(W);                 // 20,054,016 B
    ushort* h1p  = (ushort*)(W + 20054016);      // 37,879,808 B
    ushort* h2p  = (ushort*)(W + 57933824);      // 21,233,664 B
    ushort* h3   = (ushort*)(W + 79167488);      //  8,388,608 B
    ushort* w1p  = (ushort*)(W + 87556096);      //     10,240 B
    ushort* w2p  = (ushort*)(W + 87566336);      //     36,864 B
    ushort* w3p  = (ushort*)(W + 87603200);      //    147,456 B
    ushort* fcwp = (ushort*)(W + 87750656);      //  4,194,304 B
    float*  b1f  = (float*) (W + 91944960);      //        128 B
    float*  b2f  = (float*) (W + 91945088);      //        256 B
    float*  b3f  = (float*) (W + 91945344);      //        512 B
    float*  sr   = (float*) (W + 91946496);      //  8,388,608 B
    float* outp = (float*)d_out;

    k_prep_all<<<4992, 256, 0, stream>>>(w1, w2, w3, fcw, x,
                                         bn1g, bn1b, bn1m, bn1v,
                                         bn2g, bn2b, bn2m, bn2v,
                                         bn3g, bn3b, bn3m, bn3v,
                                         w1p, w2p, w3p, b1f, b2f, b3f,
                                         fcwp, x4p, h1p, h2p);
    k_conv1<<<512 * 8, 256, 0, stream>>>(x4p, w1p, b1f, h1p);
    k_conv2<<<512 * 4, 256, 0, stream>>>(h1p, w2p, b2f, h2p);
    k_conv3<<<512 * 2, 256, 0, stream>>>(h2p, w3p, b3f, h3);
    k_fc<<<dim3(8, 4, 16), 256, 0, stream>>>(h3, fcwp, sr);
    k_heads<<<512, 128, 0, stream>>>(sr, fcb, bnfg, bnfb, bnfm, bnfv,
                                     cw1, cb1, bncg, bncb, bncm, bncv, cw2, cb2,
                                     mw1, mb1, bnmg, bnmb, bnmm, bnmv, mw2, mb2, outp);
}